// Round 8
// baseline (295.410 us; speedup 1.0000x reference)
//
#include <hip/hip_runtime.h>
#include <math.h>

// Problem dims (fixed by reference)
#define BDIM 4
#define TDIM 4096
#define DDIM 1024
#define MDIM (BDIM * TDIM)   // 16384

// scan chunking
#define NC  64
#define LCH 64
static_assert(NC * LCH == TDIM, "chunking");

typedef __attribute__((ext_vector_type(8))) short short8;
typedef __attribute__((ext_vector_type(4))) float f32x4;

__device__ __forceinline__ unsigned short f2bf(float f) {
  unsigned int u = __float_as_uint(f);
  unsigned int r = (u + 0x7fffu + ((u >> 16) & 1u)) >> 16;  // RNE
  return (unsigned short)r;
}
__device__ __forceinline__ float bf2f(unsigned short h) {
  return __uint_as_float(((unsigned int)h) << 16);
}
__device__ __forceinline__ float sigmoidf_(float x) {
  return 1.0f / (1.0f + expf(-x));
}

// ---------------- prep: x -> bf16 ----------------
__global__ __launch_bounds__(256) void prep_x_kernel(const float* __restrict__ x,
                                                     unsigned short* __restrict__ xh,
                                                     int n4) {
  int i = blockIdx.x * 256 + threadIdx.x;
  if (i >= n4) return;
  float4 f = ((const float4*)x)[i];
  ushort4 h;
  h.x = f2bf(f.x);
  h.y = f2bf(f.y);
  h.z = f2bf(f.z);
  h.w = f2bf(f.w);
  ((ushort4*)xh)[i] = h;
}

// ---------------- prep: W [K][N] f32 -> transposed [N][K] bf16 ----------------
__global__ __launch_bounds__(256) void wprep_kernel(const float* __restrict__ in,
                                                    unsigned short* __restrict__ oh,
                                                    int K, int N) {
  __shared__ float t[64][65];
  int n0 = blockIdx.x * 64;
  int k0 = blockIdx.y * 64;
#pragma unroll
  for (int i = 0; i < 16; ++i) {
    int idx = i * 256 + threadIdx.x;
    int r = idx >> 6, c = idx & 63;
    t[r][c] = in[(size_t)(k0 + r) * N + (n0 + c)];
  }
  __syncthreads();
#pragma unroll
  for (int i = 0; i < 16; ++i) {
    int idx = i * 256 + threadIdx.x;
    int rn = idx >> 6, ck = idx & 63;
    oh[(size_t)(n0 + rn) * K + (k0 + ck)] = f2bf(t[ck][rn]);
  }
}

// ---------------- 256x256 8-wave GEMM: A via LDS (XOR-swizzled dbuf),
// ---------------- B direct global->register (weights are L2-resident) ----------
// A staged tile = 256 rows x 128 B = 32768 BYTES. A-buf0 @0, A-buf1 @32768.
// Swizzle: physical = row*128 + (colByte ^ ((row&7)<<4)). The +64 kk-half
// offset must be applied INSIDE the XOR (bit 6 participates in the swizzle);
// adding it post-XOR carries into the row field for rows with bit2 set
// (round-6/7 bug). Hence two hoisted bases baseA0/baseA1.

#define BARRIER()                                  \
  do {                                             \
    asm volatile("" ::: "memory");                 \
    __builtin_amdgcn_s_barrier();                  \
    asm volatile("" ::: "memory");                 \
  } while (0)

#define RD_A(SET, BUFC, H, BK)                                                  \
  _Pragma("unroll") for (int m = 0; m < 4; ++m)                                 \
      SET[m] = *(const short8*)(ldsb + (((BK) ? baseA1 : baseA0) + (BUFC) +     \
                                        (H) * 8192 + m * 2048));

#define MFMA16(ASET, BSET, HH)                                                  \
  __builtin_amdgcn_s_setprio(1);                                                \
  _Pragma("unroll") for (int m = 0; m < 4; ++m)                                 \
      _Pragma("unroll") for (int n = 0; n < 4; ++n)                             \
          acc[(HH) * 4 + m][n] = __builtin_amdgcn_mfma_f32_16x16x32_bf16(       \
              ASET[m], BSET[n], acc[(HH) * 4 + m][n], 0, 0, 0);                 \
  __builtin_amdgcn_s_setprio(0);

// one A-staging load: 16B/lane, dst = wave-uniform LDS base (+lane*16 by HW)
#define STAGE(S, BUFB, KOFF)                                                    \
  __builtin_amdgcn_global_load_lds(                                             \
      (const __attribute__((address_space(1))) unsigned int*)(AgB + off##S +    \
                                                              (KOFF)),          \
      (__attribute__((address_space(3))) unsigned int*)((char*)lds + (BUFB) +   \
                                                        (S) * 8192 +            \
                                                        wave * 1024),           \
      16, 0, 0);

// B fragment loads for K-tile T, kk half KKI (compiler-managed vmcnt)
#define BLOAD(SET, T, KKI)                                                      \
  _Pragma("unroll") for (int n = 0; n < 4; ++n)                                 \
      SET[n] = *(const short8*)(B0p + nstride[n] + ((size_t)(T) << 7) +         \
                                (KKI) * 64);

// one K-tile: B loads + A-stage at top, 4 interleaved read/MFMA clusters,
// boundary vmcnt(0) (A-stages issued ~1 tile earlier -> near-free).
#define TILE(T, BUFC, BUFN)                                                     \
  {                                                                             \
    bool pf = ((T) + 1 < NT);                                                   \
    int k1 = ((T) + 1) << 7;                                                    \
    BLOAD(b0, T, 0);                                                            \
    BLOAD(b1, T, 1);                                                            \
    if (pf) { STAGE(0, BUFN, k1) STAGE(1, BUFN, k1)                             \
              STAGE(2, BUFN, k1) STAGE(3, BUFN, k1) }                           \
    RD_A(afA, BUFC, 0, 0);                                                      \
    RD_A(afB, BUFC, 1, 0);                                                      \
    MFMA16(afA, b0, 0);                                                         \
    RD_A(afA2, BUFC, 0, 1);                                                     \
    MFMA16(afB, b0, 1);                                                         \
    RD_A(afB2, BUFC, 1, 1);                                                     \
    MFMA16(afA2, b1, 0);                                                        \
    MFMA16(afB2, b1, 1);                                                        \
    if (pf) asm volatile("s_waitcnt vmcnt(0)" ::: "memory");                    \
    BARRIER();                                                                  \
  }

// EPI 0: f32 out + bias (N = nNt*256). EPI 1: fused v|g, both bf16, ld 1024
// (col<D -> v = val, else g = sigmoid(val)).
template <int EPI>
__global__ __launch_bounds__(512, 2) void gemm8p(const unsigned short* __restrict__ A,
                                                 const unsigned short* __restrict__ B,
                                                 const float* __restrict__ bias,
                                                 float* __restrict__ outF,
                                                 unsigned short* __restrict__ outV,
                                                 unsigned short* __restrict__ outG,
                                                 int nNt, int K) {
  __shared__ unsigned short lds[32768];  // 64 KiB: A dbuf only (2 x 32768 B)

  // T1: XCD-aware swizzle (gridDim.x % 8 == 0 for all our launches)
  int cpx = gridDim.x >> 3;
  int bid = blockIdx.x;
  int swz = (bid & 7) * cpx + (bid >> 3);
  int mtile = swz / nNt, ntile = swz % nNt;

  int tid = threadIdx.x;
  int wave = tid >> 6, lane = tid & 63;
  int wm = wave >> 2, wn = wave & 3;  // 2 x 4 waves, each 128x64 output
  int rA = wm * 128 + (lane & 15);
  int rB = wn * 64 + (lane & 15);
  int kq2 = (lane >> 4) * 16;  // k-quad offset in BYTES

  // hoisted swizzled A read bases; +64 applied INSIDE the XOR (see header)
  int baseA0 = ((rA << 7) + kq2) ^ ((rA & 7) << 4);
  int baseA1 = ((rA << 7) + kq2 + 64) ^ ((rA & 7) << 4);
  const char* ldsb = (const char*)lds;

  // hoisted A staging source offsets (inverse swizzle)
#define MKOFF(S) \
  ({ int Lt = (S) * 8192 + tid * 16; int P = Lt ^ (((Lt >> 7) & 7) << 4); \
     ((P >> 7) * (K << 1)) + (P & 127); })
  int off0 = MKOFF(0), off1 = MKOFF(1), off2 = MKOFF(2), off3 = MKOFF(3);
#undef MKOFF

  const char* AgB = (const char*)(A + (size_t)(mtile * 256) * K);
  // B: per-lane fragment base (row = rB + n*16, kq within row)
  const char* B0p =
      (const char*)B + ((size_t)(ntile * 256 + rB) * K + ((lane >> 4) * 8)) * 2;
  size_t nstride[4];
#pragma unroll
  for (int n = 0; n < 4; ++n) nstride[n] = (size_t)n * ((size_t)K << 5);

  f32x4 acc[8][4] = {};
  short8 afA[4], afB[4], afA2[4], afB2[4], b0[4], b1[4];

  // prologue: stage A K-tile 0 into buf0, full drain (once)
  STAGE(0, 0, 0) STAGE(1, 0, 0) STAGE(2, 0, 0) STAGE(3, 0, 0)
  asm volatile("s_waitcnt vmcnt(0)" ::: "memory");
  BARRIER();

  int NT = K >> 6;  // 16 (even)
  for (int t = 0; t < NT; t += 2) {
    TILE(t, 0, 32768)
    TILE(t + 1, 32768, 0)
  }

  // epilogue: C/D layout col = lane&15, row = (lane>>4)*4 + j
  int row0 = mtile * 256 + wm * 128 + ((lane >> 4) << 2);
  int col0 = ntile * 256 + wn * 64 + (lane & 15);
#pragma unroll
  for (int m = 0; m < 8; ++m) {
#pragma unroll
    for (int n = 0; n < 4; ++n) {
      int col = col0 + n * 16;
      float bv = bias[col];
#pragma unroll
      for (int j = 0; j < 4; ++j) {
        int row = row0 + m * 16 + j;
        float val = acc[m][n][j] + bv;
        if (EPI == 0) {
          outF[(size_t)row * (nNt * 256) + col] = val;
        } else {
          if (col < DDIM)
            outV[(size_t)row * DDIM + col] = f2bf(val);
          else
            outG[(size_t)row * DDIM + (col - DDIM)] = f2bf(sigmoidf_(val));
        }
      }
    }
  }
}

// ---------------- SSM chunked scan (v, g in bf16) ----------------
__global__ __launch_bounds__(256) void ssm_phase1(const unsigned short* __restrict__ v,
                                                  const float* __restrict__ A,
                                                  float* __restrict__ chunkh) {
  int b = blockIdx.y, c = blockIdx.x;
  int d0 = threadIdx.x * 4;
  float4 a4 = *(const float4*)&A[d0];
  float dx = sigmoidf_(a4.x), dy = sigmoidf_(a4.y), dz = sigmoidf_(a4.z), dw = sigmoidf_(a4.w);
  float hx = 0.f, hy = 0.f, hz = 0.f, hw = 0.f;
  const ushort4* vp = (const ushort4*)(v + ((size_t)b * TDIM + (size_t)c * LCH) * DDIM + d0);
#pragma unroll 4
  for (int i = 0; i < LCH; ++i) {
    ushort4 vv = vp[(size_t)i * (DDIM / 4)];
    hx = fmaf(dx, hx, bf2f(vv.x));
    hy = fmaf(dy, hy, bf2f(vv.y));
    hz = fmaf(dz, hz, bf2f(vv.z));
    hw = fmaf(dw, hw, bf2f(vv.w));
  }
  float4 o = {hx, hy, hz, hw};
  *(float4*)&chunkh[(size_t)(b * NC + c) * DDIM + d0] = o;
}

// phase 2: exclusive carry scan across chunks, bulk-loaded into registers.
__global__ __launch_bounds__(256) void ssm_phase2(const float* __restrict__ A,
                                                  float* __restrict__ chunkh) {
  int idx = blockIdx.x * 256 + threadIdx.x;  // 0..B*D-1
  int b = idx >> 10, d = idx & 1023;
  float dec = sigmoidf_(A[d]);
  float dL = dec;
#pragma unroll
  for (int i = 0; i < 6; ++i) dL *= dL;  // dec^64
  float hv[NC];
#pragma unroll
  for (int c = 0; c < NC; ++c) hv[c] = chunkh[(size_t)(b * NC + c) * DDIM + d];
  float carry = 0.f;
#pragma unroll
  for (int c = 0; c < NC; ++c) {
    float local = hv[c];
    hv[c] = carry;
    carry = fmaf(dL, carry, local);
  }
#pragma unroll
  for (int c = 0; c < NC; ++c) chunkh[(size_t)(b * NC + c) * DDIM + d] = hv[c];
}

__global__ __launch_bounds__(256) void ssm_phase3(const unsigned short* __restrict__ v,
                                                  const unsigned short* __restrict__ g,
                                                  const float* __restrict__ A,
                                                  const float* __restrict__ C,
                                                  const float* __restrict__ chunkh,
                                                  unsigned short* __restrict__ ybf) {
  int b = blockIdx.y, c = blockIdx.x;
  int d0 = threadIdx.x * 4;
  float4 a4 = *(const float4*)&A[d0];
  float4 c4 = *(const float4*)&C[d0];
  float dx = sigmoidf_(a4.x), dy = sigmoidf_(a4.y), dz = sigmoidf_(a4.z), dw = sigmoidf_(a4.w);
  float4 h0 = *(const float4*)&chunkh[(size_t)(b * NC + c) * DDIM + d0];
  float hx = h0.x, hy = h0.y, hz = h0.z, hw = h0.w;
  size_t base = ((size_t)b * TDIM + (size_t)c * LCH) * DDIM + d0;
  const ushort4* vp = (const ushort4*)(v + base);
  const ushort4* gp = (const ushort4*)(g + base);
  ushort4* yp = (ushort4*)(ybf + base);
#pragma unroll 4
  for (int i = 0; i < LCH; ++i) {
    ushort4 vv = vp[(size_t)i * (DDIM / 4)];
    ushort4 gg = gp[(size_t)i * (DDIM / 4)];
    hx = fmaf(dx, hx, bf2f(vv.x));
    hy = fmaf(dy, hy, bf2f(vv.y));
    hz = fmaf(dz, hz, bf2f(vv.z));
    hw = fmaf(dw, hw, bf2f(vv.w));
    ushort4 yy;
    yy.x = f2bf(bf2f(gg.x) * c4.x * hx);
    yy.y = f2bf(bf2f(gg.y) * c4.y * hy);
    yy.z = f2bf(bf2f(gg.z) * c4.z * hz);
    yy.w = f2bf(bf2f(gg.w) * c4.w * hw);
    yp[(size_t)i * (DDIM / 4)] = yy;
  }
}

extern "C" void kernel_launch(void* const* d_in, const int* in_sizes, int n_in,
                              void* d_out, int out_size, void* d_ws, size_t ws_size,
                              hipStream_t stream) {
  const float* x = (const float*)d_in[0];
  const float* W_in = (const float*)d_in[1];
  const float* b_in = (const float*)d_in[2];
  const float* A = (const float*)d_in[3];
  const float* C = (const float*)d_in[4];
  const float* W_out = (const float*)d_in[5];
  const float* b_out = (const float*)d_in[6];
  float* out = (float*)d_out;

  // workspace carve (~142 MB)
  char* ws = (char*)d_ws;
  const size_t MK = (size_t)MDIM * DDIM;  // 16,777,216
  unsigned short* xh = (unsigned short*)ws;    ws += MK * 2;                       // 33.5 MB
  unsigned short* winh = (unsigned short*)ws;  ws += (size_t)2 * DDIM * DDIM * 2;  // 4.2 MB
  unsigned short* wouth = (unsigned short*)ws; ws += (size_t)DDIM * DDIM * 2;      // 2.1 MB
  unsigned short* v = (unsigned short*)ws;     ws += MK * 2;                       // 33.5 MB
  unsigned short* g = (unsigned short*)ws;     ws += MK * 2;                       // 33.5 MB
  unsigned short* ybf = (unsigned short*)ws;   ws += MK * 2;                       // 33.5 MB
  float* chunkh = (float*)ws;                  ws += (size_t)BDIM * NC * DDIM * 4; // 1.0 MB

  // prep
  prep_x_kernel<<<(int)(MK / 4 / 256), 256, 0, stream>>>(x, xh, (int)(MK / 4));
  wprep_kernel<<<dim3(2 * DDIM / 64, DDIM / 64), 256, 0, stream>>>(W_in, winh, DDIM, 2 * DDIM);
  wprep_kernel<<<dim3(DDIM / 64, DDIM / 64), 256, 0, stream>>>(W_out, wouth, DDIM, DDIM);

  // fused GEMM1: [v | g] = x @ W_in + b_in ; v bf16, g = sigmoid -> bf16
  gemm8p<1><<<(MDIM / 256) * 8, 512, 0, stream>>>(xh, winh, b_in, nullptr, v, g, 8, DDIM);

  // chunked scan
  ssm_phase1<<<dim3(NC, BDIM), 256, 0, stream>>>(v, A, chunkh);
  ssm_phase2<<<(BDIM * DDIM) / 256, 256, 0, stream>>>(A, chunkh);
  ssm_phase3<<<dim3(NC, BDIM), 256, 0, stream>>>(v, g, A, C, chunkh, ybf);

  // GEMM2: out = y @ W_out + b_out
  gemm8p<0><<<(MDIM / 256) * 4, 512, 0, stream>>>(ybf, wouth, b_out, out, nullptr, nullptr,
                                                  4, DDIM);
}

// Round 9
// 284.843 us; speedup vs baseline: 1.0371x; 1.0371x over previous
//
#include <hip/hip_runtime.h>
#include <math.h>

// Problem dims (fixed by reference)
#define BDIM 4
#define TDIM 4096
#define DDIM 1024
#define MDIM (BDIM * TDIM)   // 16384

// scan chunking
#define NC  64
#define LCH 64
static_assert(NC * LCH == TDIM, "chunking");

typedef __attribute__((ext_vector_type(8))) short short8;
typedef __attribute__((ext_vector_type(4))) float f32x4;

__device__ __forceinline__ unsigned short f2bf(float f) {
  unsigned int u = __float_as_uint(f);
  unsigned int r = (u + 0x7fffu + ((u >> 16) & 1u)) >> 16;  // RNE
  return (unsigned short)r;
}
__device__ __forceinline__ float bf2f(unsigned short h) {
  return __uint_as_float(((unsigned int)h) << 16);
}
__device__ __forceinline__ float sigmoidf_(float x) {
  return 1.0f / (1.0f + expf(-x));
}

// ---------------- prep: x -> bf16 ----------------
__global__ __launch_bounds__(256) void prep_x_kernel(const float* __restrict__ x,
                                                     unsigned short* __restrict__ xh,
                                                     int n4) {
  int i = blockIdx.x * 256 + threadIdx.x;
  if (i >= n4) return;
  float4 f = ((const float4*)x)[i];
  ushort4 h;
  h.x = f2bf(f.x);
  h.y = f2bf(f.y);
  h.z = f2bf(f.z);
  h.w = f2bf(f.w);
  ((ushort4*)xh)[i] = h;
}

// ---------------- prep: W [K][N] f32 -> transposed [N][K] bf16 ----------------
__global__ __launch_bounds__(256) void wprep_kernel(const float* __restrict__ in,
                                                    unsigned short* __restrict__ oh,
                                                    int K, int N) {
  __shared__ float t[64][65];
  int n0 = blockIdx.x * 64;
  int k0 = blockIdx.y * 64;
#pragma unroll
  for (int i = 0; i < 16; ++i) {
    int idx = i * 256 + threadIdx.x;
    int r = idx >> 6, c = idx & 63;
    t[r][c] = in[(size_t)(k0 + r) * N + (n0 + c)];
  }
  __syncthreads();
#pragma unroll
  for (int i = 0; i < 16; ++i) {
    int idx = i * 256 + threadIdx.x;
    int rn = idx >> 6, ck = idx & 63;
    oh[(size_t)(n0 + rn) * K + (k0 + ck)] = f2bf(t[ck][rn]);
  }
}

// ---------------- 128x128 4-wave GEMM, 3 blocks/CU:
// A via XOR-swizzled LDS dbuf (16 KB/tile: 128 rows x 128 B; buf0 @0, buf1 @16384),
// B direct global->register (weights L2-resident; latency covered by occupancy).
// Swizzle: physical = row*128 + (colByte ^ ((row&7)<<4)); the +64 kk-half offset
// applied INSIDE the XOR (round-7 lesson). global_load_lds writes linearly;
// source carries the inverse swizzle.

#define BARRIER()                                  \
  do {                                             \
    asm volatile("" ::: "memory");                 \
    __builtin_amdgcn_s_barrier();                  \
    asm volatile("" ::: "memory");                 \
  } while (0)

#define RD_A(SET, BUFC, BK)                                                     \
  _Pragma("unroll") for (int m = 0; m < 4; ++m)                                 \
      SET[m] = *(const short8*)(ldsb + (((BK) ? baseA1 : baseA0) + (BUFC) +     \
                                        m * 2048));

#define MFMA16(ASET, BSET)                                                      \
  __builtin_amdgcn_s_setprio(1);                                                \
  _Pragma("unroll") for (int m = 0; m < 4; ++m)                                 \
      _Pragma("unroll") for (int n = 0; n < 4; ++n)                             \
          acc[m][n] = __builtin_amdgcn_mfma_f32_16x16x32_bf16(                  \
              ASET[m], BSET[n], acc[m][n], 0, 0, 0);                            \
  __builtin_amdgcn_s_setprio(0);

// one A-staging load: 16B/lane, dst = wave-uniform LDS base (+lane*16 by HW)
#define STAGE(S, BUFB, KOFF)                                                    \
  __builtin_amdgcn_global_load_lds(                                             \
      (const __attribute__((address_space(1))) unsigned int*)(AgB + off##S +    \
                                                              (KOFF)),          \
      (__attribute__((address_space(3))) unsigned int*)((char*)lds + (BUFB) +   \
                                                        (S) * 4096 +            \
                                                        wave * 1024),           \
      16, 0, 0);

// B fragment loads for K-tile T, kk half KKI (math verified in round 8)
#define BLOAD(SET, T, KKI)                                                      \
  _Pragma("unroll") for (int n = 0; n < 4; ++n)                                 \
      SET[n] = *(const short8*)(B0p + nstride[n] + ((size_t)(T) << 7) +         \
                                (KKI) * 64);

// one K-tile: B loads + next-tile A-stages at top, 2 read/MFMA clusters,
// boundary vmcnt(0) (stages + consumed B loads; issued a full tile earlier).
#define TILE(T, BUFC, BUFN)                                                     \
  {                                                                             \
    bool pf = ((T) + 1 < NT);                                                   \
    int k1 = ((T) + 1) << 7;                                                    \
    BLOAD(b0, T, 0);                                                            \
    BLOAD(b1, T, 1);                                                            \
    if (pf) { STAGE(0, BUFN, k1) STAGE(1, BUFN, k1)                             \
              STAGE(2, BUFN, k1) STAGE(3, BUFN, k1) }                           \
    RD_A(af, BUFC, 0);                                                          \
    MFMA16(af, b0);                                                             \
    RD_A(af2, BUFC, 1);                                                         \
    MFMA16(af2, b1);                                                            \
    if (pf) asm volatile("s_waitcnt vmcnt(0)" ::: "memory");                    \
    BARRIER();                                                                  \
  }

// EPI 0: f32 out + bias (N = nNt*128). EPI 1: fused v|g, both bf16, ld 1024
// (col<D -> v = val, else g = sigmoid(val)).
template <int EPI>
__global__ __launch_bounds__(256, 3) void gemm4w(const unsigned short* __restrict__ A,
                                                 const unsigned short* __restrict__ B,
                                                 const float* __restrict__ bias,
                                                 float* __restrict__ outF,
                                                 unsigned short* __restrict__ outV,
                                                 unsigned short* __restrict__ outG,
                                                 int nNt, int K) {
  __shared__ unsigned short lds[16384];  // 32 KiB: A dbuf (2 x 16384 B)

  // T1: XCD-aware swizzle (gridDim.x % 8 == 0 for all our launches)
  int cpx = gridDim.x >> 3;
  int bid = blockIdx.x;
  int swz = (bid & 7) * cpx + (bid >> 3);
  int mtile = swz / nNt, ntile = swz % nNt;

  int tid = threadIdx.x;
  int wave = tid >> 6, lane = tid & 63;
  int wm = wave >> 1, wn = wave & 1;  // 2 x 2 waves, each 64x64 output
  int rA = wm * 64 + (lane & 15);
  int kq2 = (lane >> 4) * 16;  // k-quad offset in BYTES

  // hoisted swizzled A read bases; +64 applied INSIDE the XOR
  int baseA0 = ((rA << 7) + kq2) ^ ((rA & 7) << 4);
  int baseA1 = ((rA << 7) + kq2 + 64) ^ ((rA & 7) << 4);
  const char* ldsb = (const char*)lds;

  // hoisted A staging source offsets (inverse swizzle; tile = 128 rows x 128 B)
#define MKOFF(S) \
  ({ int Lt = (S) * 4096 + tid * 16; int P = Lt ^ (((Lt >> 7) & 7) << 4); \
     ((P >> 7) * (K << 1)) + (P & 127); })
  int off0 = MKOFF(0), off1 = MKOFF(1), off2 = MKOFF(2), off3 = MKOFF(3);
#undef MKOFF

  const char* AgB = (const char*)(A + (size_t)(mtile * 128) * K);
  // B: per-lane fragment base (row = ntile*128 + wn*64 + (lane&15) + n*16)
  const char* B0p =
      (const char*)B +
      ((size_t)(ntile * 128 + wn * 64 + (lane & 15)) * K + ((lane >> 4) * 8)) * 2;
  size_t nstride[4];
#pragma unroll
  for (int n = 0; n < 4; ++n) nstride[n] = (size_t)n * ((size_t)K << 5);

  f32x4 acc[4][4] = {};
  short8 af[4], af2[4], b0[4], b1[4];

  // prologue: stage A K-tile 0 into buf0, full drain (once)
  STAGE(0, 0, 0) STAGE(1, 0, 0) STAGE(2, 0, 0) STAGE(3, 0, 0)
  asm volatile("s_waitcnt vmcnt(0)" ::: "memory");
  BARRIER();

  int NT = K >> 6;  // 16 (even)
  for (int t = 0; t < NT; t += 2) {
    TILE(t, 0, 16384)
    TILE(t + 1, 16384, 0)
  }

  // epilogue: C/D layout col = lane&15, row = (lane>>4)*4 + j
  int row0 = mtile * 128 + wm * 64 + ((lane >> 4) << 2);
  int col0 = ntile * 128 + wn * 64 + (lane & 15);
#pragma unroll
  for (int m = 0; m < 4; ++m) {
#pragma unroll
    for (int n = 0; n < 4; ++n) {
      int col = col0 + n * 16;
      float bv = bias[col];
#pragma unroll
      for (int j = 0; j < 4; ++j) {
        int row = row0 + m * 16 + j;
        float val = acc[m][n][j] + bv;
        if (EPI == 0) {
          outF[(size_t)row * (nNt * 128) + col] = val;
        } else {
          if (col < DDIM)
            outV[(size_t)row * DDIM + col] = f2bf(val);
          else
            outG[(size_t)row * DDIM + (col - DDIM)] = f2bf(sigmoidf_(val));
        }
      }
    }
  }
}

// ---------------- SSM chunked scan (v, g in bf16) ----------------
__global__ __launch_bounds__(256) void ssm_phase1(const unsigned short* __restrict__ v,
                                                  const float* __restrict__ A,
                                                  float* __restrict__ chunkh) {
  int b = blockIdx.y, c = blockIdx.x;
  int d0 = threadIdx.x * 4;
  float4 a4 = *(const float4*)&A[d0];
  float dx = sigmoidf_(a4.x), dy = sigmoidf_(a4.y), dz = sigmoidf_(a4.z), dw = sigmoidf_(a4.w);
  float hx = 0.f, hy = 0.f, hz = 0.f, hw = 0.f;
  const ushort4* vp = (const ushort4*)(v + ((size_t)b * TDIM + (size_t)c * LCH) * DDIM + d0);
#pragma unroll 4
  for (int i = 0; i < LCH; ++i) {
    ushort4 vv = vp[(size_t)i * (DDIM / 4)];
    hx = fmaf(dx, hx, bf2f(vv.x));
    hy = fmaf(dy, hy, bf2f(vv.y));
    hz = fmaf(dz, hz, bf2f(vv.z));
    hw = fmaf(dw, hw, bf2f(vv.w));
  }
  float4 o = {hx, hy, hz, hw};
  *(float4*)&chunkh[(size_t)(b * NC + c) * DDIM + d0] = o;
}

// phase 2: exclusive carry scan across chunks, bulk-loaded into registers.
__global__ __launch_bounds__(256) void ssm_phase2(const float* __restrict__ A,
                                                  float* __restrict__ chunkh) {
  int idx = blockIdx.x * 256 + threadIdx.x;  // 0..B*D-1
  int b = idx >> 10, d = idx & 1023;
  float dec = sigmoidf_(A[d]);
  float dL = dec;
#pragma unroll
  for (int i = 0; i < 6; ++i) dL *= dL;  // dec^64
  float hv[NC];
#pragma unroll
  for (int c = 0; c < NC; ++c) hv[c] = chunkh[(size_t)(b * NC + c) * DDIM + d];
  float carry = 0.f;
#pragma unroll
  for (int c = 0; c < NC; ++c) {
    float local = hv[c];
    hv[c] = carry;
    carry = fmaf(dL, carry, local);
  }
#pragma unroll
  for (int c = 0; c < NC; ++c) chunkh[(size_t)(b * NC + c) * DDIM + d] = hv[c];
}

__global__ __launch_bounds__(256) void ssm_phase3(const unsigned short* __restrict__ v,
                                                  const unsigned short* __restrict__ g,
                                                  const float* __restrict__ A,
                                                  const float* __restrict__ C,
                                                  const float* __restrict__ chunkh,
                                                  unsigned short* __restrict__ ybf) {
  int b = blockIdx.y, c = blockIdx.x;
  int d0 = threadIdx.x * 4;
  float4 a4 = *(const float4*)&A[d0];
  float4 c4 = *(const float4*)&C[d0];
  float dx = sigmoidf_(a4.x), dy = sigmoidf_(a4.y), dz = sigmoidf_(a4.z), dw = sigmoidf_(a4.w);
  float4 h0 = *(const float4*)&chunkh[(size_t)(b * NC + c) * DDIM + d0];
  float hx = h0.x, hy = h0.y, hz = h0.z, hw = h0.w;
  size_t base = ((size_t)b * TDIM + (size_t)c * LCH) * DDIM + d0;
  const ushort4* vp = (const ushort4*)(v + base);
  const ushort4* gp = (const ushort4*)(g + base);
  ushort4* yp = (ushort4*)(ybf + base);
#pragma unroll 4
  for (int i = 0; i < LCH; ++i) {
    ushort4 vv = vp[(size_t)i * (DDIM / 4)];
    ushort4 gg = gp[(size_t)i * (DDIM / 4)];
    hx = fmaf(dx, hx, bf2f(vv.x));
    hy = fmaf(dy, hy, bf2f(vv.y));
    hz = fmaf(dz, hz, bf2f(vv.z));
    hw = fmaf(dw, hw, bf2f(vv.w));
    ushort4 yy;
    yy.x = f2bf(bf2f(gg.x) * c4.x * hx);
    yy.y = f2bf(bf2f(gg.y) * c4.y * hy);
    yy.z = f2bf(bf2f(gg.z) * c4.z * hz);
    yy.w = f2bf(bf2f(gg.w) * c4.w * hw);
    yp[(size_t)i * (DDIM / 4)] = yy;
  }
}

extern "C" void kernel_launch(void* const* d_in, const int* in_sizes, int n_in,
                              void* d_out, int out_size, void* d_ws, size_t ws_size,
                              hipStream_t stream) {
  const float* x = (const float*)d_in[0];
  const float* W_in = (const float*)d_in[1];
  const float* b_in = (const float*)d_in[2];
  const float* A = (const float*)d_in[3];
  const float* C = (const float*)d_in[4];
  const float* W_out = (const float*)d_in[5];
  const float* b_out = (const float*)d_in[6];
  float* out = (float*)d_out;

  // workspace carve (~142 MB)
  char* ws = (char*)d_ws;
  const size_t MK = (size_t)MDIM * DDIM;  // 16,777,216
  unsigned short* xh = (unsigned short*)ws;    ws += MK * 2;                       // 33.5 MB
  unsigned short* winh = (unsigned short*)ws;  ws += (size_t)2 * DDIM * DDIM * 2;  // 4.2 MB
  unsigned short* wouth = (unsigned short*)ws; ws += (size_t)DDIM * DDIM * 2;      // 2.1 MB
  unsigned short* v = (unsigned short*)ws;     ws += MK * 2;                       // 33.5 MB
  unsigned short* g = (unsigned short*)ws;     ws += MK * 2;                       // 33.5 MB
  unsigned short* ybf = (unsigned short*)ws;   ws += MK * 2;                       // 33.5 MB
  float* chunkh = (float*)ws;                  ws += (size_t)BDIM * NC * DDIM * 4; // 1.0 MB

  // prep
  prep_x_kernel<<<(int)(MK / 4 / 256), 256, 0, stream>>>(x, xh, (int)(MK / 4));
  wprep_kernel<<<dim3(2 * DDIM / 64, DDIM / 64), 256, 0, stream>>>(W_in, winh, DDIM, 2 * DDIM);
  wprep_kernel<<<dim3(DDIM / 64, DDIM / 64), 256, 0, stream>>>(W_out, wouth, DDIM, DDIM);

  // fused GEMM1: [v | g] = x @ W_in + b_in ; v bf16, g = sigmoid -> bf16
  gemm4w<1><<<(MDIM / 128) * 16, 256, 0, stream>>>(xh, winh, b_in, nullptr, v, g, 16, DDIM);

  // chunked scan
  ssm_phase1<<<dim3(NC, BDIM), 256, 0, stream>>>(v, A, chunkh);
  ssm_phase2<<<(BDIM * DDIM) / 256, 256, 0, stream>>>(A, chunkh);
  ssm_phase3<<<dim3(NC, BDIM), 256, 0, stream>>>(v, g, A, C, chunkh, ybf);

  // GEMM2: out = y @ W_out + b_out
  gemm4w<0><<<(MDIM / 128) * 8, 256, 0, stream>>>(ybf, wouth, b_out, out, nullptr, nullptr,
                                                  8, DDIM);
}

// Round 10
// 183.885 us; speedup vs baseline: 1.6065x; 1.5490x over previous
//
#include <hip/hip_runtime.h>
#include <math.h>

// Problem dims (fixed by reference)
#define BDIM 4
#define TDIM 4096
#define DDIM 1024
#define MDIM (BDIM * TDIM)   // 16384

// scan chunking
#define NC  64
#define LCH 64
static_assert(NC * LCH == TDIM, "chunking");

typedef __attribute__((ext_vector_type(8))) short short8;
typedef __attribute__((ext_vector_type(4))) float f32x4;

__device__ __forceinline__ unsigned short f2bf(float f) {
  unsigned int u = __float_as_uint(f);
  unsigned int r = (u + 0x7fffu + ((u >> 16) & 1u)) >> 16;  // RNE
  return (unsigned short)r;
}
__device__ __forceinline__ float bf2f(unsigned short h) {
  return __uint_as_float(((unsigned int)h) << 16);
}
__device__ __forceinline__ float sigmoidf_(float x) {
  return 1.0f / (1.0f + expf(-x));
}

// ---------------- prep: x -> bf16 ----------------
__global__ __launch_bounds__(256) void prep_x_kernel(const float* __restrict__ x,
                                                     unsigned short* __restrict__ xh,
                                                     int n4) {
  int i = blockIdx.x * 256 + threadIdx.x;
  if (i >= n4) return;
  float4 f = ((const float4*)x)[i];
  ushort4 h;
  h.x = f2bf(f.x);
  h.y = f2bf(f.y);
  h.z = f2bf(f.z);
  h.w = f2bf(f.w);
  ((ushort4*)xh)[i] = h;
}

// ---------------- prep: W [K][N] f32 -> transposed [N][K] bf16 ----------------
__global__ __launch_bounds__(256) void wprep_kernel(const float* __restrict__ in,
                                                    unsigned short* __restrict__ oh,
                                                    int K, int N) {
  __shared__ float t[64][65];
  int n0 = blockIdx.x * 64;
  int k0 = blockIdx.y * 64;
#pragma unroll
  for (int i = 0; i < 16; ++i) {
    int idx = i * 256 + threadIdx.x;
    int r = idx >> 6, c = idx & 63;
    t[r][c] = in[(size_t)(k0 + r) * N + (n0 + c)];
  }
  __syncthreads();
#pragma unroll
  for (int i = 0; i < 16; ++i) {
    int idx = i * 256 + threadIdx.x;
    int rn = idx >> 6, ck = idx & 63;
    oh[(size_t)(n0 + rn) * K + (k0 + ck)] = f2bf(t[ck][rn]);
  }
}

// ---------------- 256x256 8-wave GEMM, BK=64, 8-phase schedule ----------------
// Substrate identical to round 5 (verified): A dbuf @0/@32768, B dbuf @65536/@98304
// (each staged tile 256 rows x 128 B = 32768 bytes). Swizzle: physical =
// row*128 + (colByte ^ ((row&7)<<4)); +64 kk-half offset applied INSIDE the XOR.
// global_load_lds writes linearly; source carries the inverse swizzle.
// NEW: m201-style phase schedule — per K-tile 4 phases, each
// {ds_reads quadrant -> stage-issue -> barrier -> setprio MFMA -> barrier};
// stages for t+1 spread A|A|B|-; single vmcnt(0) at phase-4 tail.

#define BARRIER()                                  \
  do {                                             \
    asm volatile("" ::: "memory");                 \
    __builtin_amdgcn_s_barrier();                  \
    asm volatile("" ::: "memory");                 \
  } while (0)

#define RD_A(SET, BUFC, H, BK)                                                  \
  _Pragma("unroll") for (int m = 0; m < 4; ++m)                                 \
      SET[m] = *(const short8*)(ldsb + (((BK) ? baseA1 : baseA0) + (BUFC) +     \
                                        (H) * 8192 + m * 2048));

#define RD_B(SET, BUFC, BK)                                                     \
  _Pragma("unroll") for (int n = 0; n < 4; ++n)                                 \
      SET[n] = *(const short8*)(ldsbB + (((BK) ? baseB1 : baseB0) + (BUFC) +    \
                                         n * 2048));

#define MFMA16(ASET, BSET, HH)                                                  \
  __builtin_amdgcn_s_setprio(1);                                                \
  _Pragma("unroll") for (int m = 0; m < 4; ++m)                                 \
      _Pragma("unroll") for (int n = 0; n < 4; ++n)                             \
          acc[(HH) * 4 + m][n] = __builtin_amdgcn_mfma_f32_16x16x32_bf16(       \
              ASET[m], BSET[n], acc[(HH) * 4 + m][n], 0, 0, 0);                 \
  __builtin_amdgcn_s_setprio(0);

// one staging load: 16B per lane, dst = wave-uniform LDS base (+lane*16 by HW)
#define STAGE(PTR, S, BUFB, KOFF)                                               \
  __builtin_amdgcn_global_load_lds(                                             \
      (const __attribute__((address_space(1))) unsigned int*)((PTR) + off##S +  \
                                                              (KOFF)),         \
      (__attribute__((address_space(3))) unsigned int*)((char*)lds + (BUFB) +   \
                                                        (S) * 8192 +            \
                                                        wave * 1024),           \
      16, 0, 0);

// one K-tile, 4 phases. PF is a literal (loop peeled).
#define TILE8(T, BUFC, BUFN, PF)                                                \
  {                                                                             \
    int k1 = ((T) + 1) << 7; /* byte advance per K-tile */                      \
    /* ph1: A(H0,kk0)+B(kk0) reads; stage A-units S0,S2 for t+1 */              \
    RD_A(afA, BUFC, 0, 0);                                                      \
    RD_B(bfr, BUFC, 0);                                                         \
    if (PF) { STAGE(AgB, 0, BUFN, k1) STAGE(AgB, 2, BUFN, k1) }                 \
    BARRIER();                                                                  \
    MFMA16(afA, bfr, 0);                                                        \
    BARRIER();                                                                  \
    /* ph2: A(H1,kk0) reads; stage A-units S1,S3 */                             \
    RD_A(afB, BUFC, 1, 0);                                                      \
    if (PF) { STAGE(AgB, 1, BUFN, k1) STAGE(AgB, 3, BUFN, k1) }                 \
    BARRIER();                                                                  \
    MFMA16(afB, bfr, 1);                                                        \
    BARRIER();                                                                  \
    /* ph3: A(H0,kk1)+B(kk1) reads; stage all 4 B-units */                      \
    RD_A(afA, BUFC, 0, 1);                                                      \
    RD_B(bfr, BUFC, 1);                                                         \
    if (PF) { STAGE(BgB, 0, 65536 + (BUFN), k1) STAGE(BgB, 1, 65536 + (BUFN), k1) \
              STAGE(BgB, 2, 65536 + (BUFN), k1) STAGE(BgB, 3, 65536 + (BUFN), k1) } \
    BARRIER();                                                                  \
    MFMA16(afA, bfr, 0);                                                        \
    BARRIER();                                                                  \
    /* ph4: A(H1,kk1) reads; boundary drain */                                  \
    RD_A(afB, BUFC, 1, 1);                                                      \
    BARRIER();                                                                  \
    MFMA16(afB, bfr, 1);                                                        \
    if (PF) asm volatile("s_waitcnt vmcnt(0)" ::: "memory");                    \
    BARRIER();                                                                  \
  }

// EPI 0: f32 out + bias (N = nNt*256). EPI 1: fused v|g, both bf16, ld 1024
// (col<D -> v = val, else g = sigmoid(val)).
template <int EPI>
__global__ __launch_bounds__(512, 2) void gemm8p(const unsigned short* __restrict__ A,
                                                 const unsigned short* __restrict__ B,
                                                 const float* __restrict__ bias,
                                                 float* __restrict__ outF,
                                                 unsigned short* __restrict__ outV,
                                                 unsigned short* __restrict__ outG,
                                                 int nNt, int K) {
  __shared__ unsigned short lds[65536];  // 128 KiB

  // T1: XCD-aware swizzle (gridDim.x % 8 == 0 for all our launches)
  int cpx = gridDim.x >> 3;
  int bid = blockIdx.x;
  int swz = (bid & 7) * cpx + (bid >> 3);
  int mtile = swz / nNt, ntile = swz % nNt;

  int tid = threadIdx.x;
  int wave = tid >> 6, lane = tid & 63;
  int wm = wave >> 2, wn = wave & 3;  // 2 x 4 waves, each 128x64 output
  int rA = wm * 128 + (lane & 15);
  int rB = wn * 64 + (lane & 15);
  int kq2 = (lane >> 4) * 16;  // k-quad offset in BYTES

  // hoisted swizzled read bases (+64 inside the XOR — round-7 lesson)
  int baseA0 = ((rA << 7) + kq2) ^ ((rA & 7) << 4);
  int baseA1 = ((rA << 7) + kq2 + 64) ^ ((rA & 7) << 4);
  int baseB0 = ((rB << 7) + kq2) ^ ((rB & 7) << 4);
  int baseB1 = ((rB << 7) + kq2 + 64) ^ ((rB & 7) << 4);
  const char* ldsb = (const char*)lds;
  const char* ldsbB = (const char*)lds + 65536;

  // hoisted staging source offsets (inverse swizzle; same geometry A and B)
#define MKOFF(S) \
  ({ int Lt = (S) * 8192 + tid * 16; int P = Lt ^ (((Lt >> 7) & 7) << 4); \
     ((P >> 7) * (K << 1)) + (P & 127); })
  int off0 = MKOFF(0), off1 = MKOFF(1), off2 = MKOFF(2), off3 = MKOFF(3);
#undef MKOFF

  const char* AgB = (const char*)(A + (size_t)(mtile * 256) * K);
  const char* BgB = (const char*)(B + (size_t)(ntile * 256) * K);

  f32x4 acc[8][4] = {};
  short8 afA[4], afB[4], bfr[4];

  // prologue: stage K-tile 0 into buf0 (A @0, B @65536), full drain (once)
  STAGE(AgB, 0, 0, 0) STAGE(AgB, 1, 0, 0) STAGE(AgB, 2, 0, 0) STAGE(AgB, 3, 0, 0)
  STAGE(BgB, 0, 65536, 0) STAGE(BgB, 1, 65536, 0)
  STAGE(BgB, 2, 65536, 0) STAGE(BgB, 3, 65536, 0)
  asm volatile("s_waitcnt vmcnt(0)" ::: "memory");
  BARRIER();

  // NT = K/64 = 16 always (K == DDIM for both GEMMs); peel the last tile.
  for (int t = 0; t < 14; t += 2) {
    TILE8(t, 0, 32768, 1)
    TILE8(t + 1, 32768, 0, 1)
  }
  TILE8(14, 0, 32768, 1)
  TILE8(15, 32768, 0, 0)

  // epilogue: C/D layout col = lane&15, row = (lane>>4)*4 + j
  int row0 = mtile * 256 + wm * 128 + ((lane >> 4) << 2);
  int col0 = ntile * 256 + wn * 64 + (lane & 15);
#pragma unroll
  for (int m = 0; m < 8; ++m) {
#pragma unroll
    for (int n = 0; n < 4; ++n) {
      int col = col0 + n * 16;
      float bv = bias[col];
#pragma unroll
      for (int j = 0; j < 4; ++j) {
        int row = row0 + m * 16 + j;
        float val = acc[m][n][j] + bv;
        if (EPI == 0) {
          outF[(size_t)row * (nNt * 256) + col] = val;
        } else {
          if (col < DDIM)
            outV[(size_t)row * DDIM + col] = f2bf(val);
          else
            outG[(size_t)row * DDIM + (col - DDIM)] = f2bf(sigmoidf_(val));
        }
      }
    }
  }
}

// ---------------- SSM chunked scan (v, g in bf16) ----------------
__global__ __launch_bounds__(256) void ssm_phase1(const unsigned short* __restrict__ v,
                                                  const float* __restrict__ A,
                                                  float* __restrict__ chunkh) {
  int b = blockIdx.y, c = blockIdx.x;
  int d0 = threadIdx.x * 4;
  float4 a4 = *(const float4*)&A[d0];
  float dx = sigmoidf_(a4.x), dy = sigmoidf_(a4.y), dz = sigmoidf_(a4.z), dw = sigmoidf_(a4.w);
  float hx = 0.f, hy = 0.f, hz = 0.f, hw = 0.f;
  const ushort4* vp = (const ushort4*)(v + ((size_t)b * TDIM + (size_t)c * LCH) * DDIM + d0);
#pragma unroll 4
  for (int i = 0; i < LCH; ++i) {
    ushort4 vv = vp[(size_t)i * (DDIM / 4)];
    hx = fmaf(dx, hx, bf2f(vv.x));
    hy = fmaf(dy, hy, bf2f(vv.y));
    hz = fmaf(dz, hz, bf2f(vv.z));
    hw = fmaf(dw, hw, bf2f(vv.w));
  }
  float4 o = {hx, hy, hz, hw};
  *(float4*)&chunkh[(size_t)(b * NC + c) * DDIM + d0] = o;
}

// phase 2: exclusive carry scan across chunks, bulk-loaded into registers.
__global__ __launch_bounds__(256) void ssm_phase2(const float* __restrict__ A,
                                                  float* __restrict__ chunkh) {
  int idx = blockIdx.x * 256 + threadIdx.x;  // 0..B*D-1
  int b = idx >> 10, d = idx & 1023;
  float dec = sigmoidf_(A[d]);
  float dL = dec;
#pragma unroll
  for (int i = 0; i < 6; ++i) dL *= dL;  // dec^64
  float hv[NC];
#pragma unroll
  for (int c = 0; c < NC; ++c) hv[c] = chunkh[(size_t)(b * NC + c) * DDIM + d];
  float carry = 0.f;
#pragma unroll
  for (int c = 0; c < NC; ++c) {
    float local = hv[c];
    hv[c] = carry;
    carry = fmaf(dL, carry, local);
  }
#pragma unroll
  for (int c = 0; c < NC; ++c) chunkh[(size_t)(b * NC + c) * DDIM + d] = hv[c];
}

__global__ __launch_bounds__(256) void ssm_phase3(const unsigned short* __restrict__ v,
                                                  const unsigned short* __restrict__ g,
                                                  const float* __restrict__ A,
                                                  const float* __restrict__ C,
                                                  const float* __restrict__ chunkh,
                                                  unsigned short* __restrict__ ybf) {
  int b = blockIdx.y, c = blockIdx.x;
  int d0 = threadIdx.x * 4;
  float4 a4 = *(const float4*)&A[d0];
  float4 c4 = *(const float4*)&C[d0];
  float dx = sigmoidf_(a4.x), dy = sigmoidf_(a4.y), dz = sigmoidf_(a4.z), dw = sigmoidf_(a4.w);
  float4 h0 = *(const float4*)&chunkh[(size_t)(b * NC + c) * DDIM + d0];
  float hx = h0.x, hy = h0.y, hz = h0.z, hw = h0.w;
  size_t base = ((size_t)b * TDIM + (size_t)c * LCH) * DDIM + d0;
  const ushort4* vp = (const ushort4*)(v + base);
  const ushort4* gp = (const ushort4*)(g + base);
  ushort4* yp = (ushort4*)(ybf + base);
#pragma unroll 4
  for (int i = 0; i < LCH; ++i) {
    ushort4 vv = vp[(size_t)i * (DDIM / 4)];
    ushort4 gg = gp[(size_t)i * (DDIM / 4)];
    hx = fmaf(dx, hx, bf2f(vv.x));
    hy = fmaf(dy, hy, bf2f(vv.y));
    hz = fmaf(dz, hz, bf2f(vv.z));
    hw = fmaf(dw, hw, bf2f(vv.w));
    ushort4 yy;
    yy.x = f2bf(bf2f(gg.x) * c4.x * hx);
    yy.y = f2bf(bf2f(gg.y) * c4.y * hy);
    yy.z = f2bf(bf2f(gg.z) * c4.z * hz);
    yy.w = f2bf(bf2f(gg.w) * c4.w * hw);
    yp[(size_t)i * (DDIM / 4)] = yy;
  }
}

extern "C" void kernel_launch(void* const* d_in, const int* in_sizes, int n_in,
                              void* d_out, int out_size, void* d_ws, size_t ws_size,
                              hipStream_t stream) {
  const float* x = (const float*)d_in[0];
  const float* W_in = (const float*)d_in[1];
  const float* b_in = (const float*)d_in[2];
  const float* A = (const float*)d_in[3];
  const float* C = (const float*)d_in[4];
  const float* W_out = (const float*)d_in[5];
  const float* b_out = (const float*)d_in[6];
  float* out = (float*)d_out;

  // workspace carve (~142 MB)
  char* ws = (char*)d_ws;
  const size_t MK = (size_t)MDIM * DDIM;  // 16,777,216
  unsigned short* xh = (unsigned short*)ws;    ws += MK * 2;                       // 33.5 MB
  unsigned short* winh = (unsigned short*)ws;  ws += (size_t)2 * DDIM * DDIM * 2;  // 4.2 MB
  unsigned short* wouth = (unsigned short*)ws; ws += (size_t)DDIM * DDIM * 2;      // 2.1 MB
  unsigned short* v = (unsigned short*)ws;     ws += MK * 2;                       // 33.5 MB
  unsigned short* g = (unsigned short*)ws;     ws += MK * 2;                       // 33.5 MB
  unsigned short* ybf = (unsigned short*)ws;   ws += MK * 2;                       // 33.5 MB
  float* chunkh = (float*)ws;                  ws += (size_t)BDIM * NC * DDIM * 4; // 1.0 MB

  // prep
  prep_x_kernel<<<(int)(MK / 4 / 256), 256, 0, stream>>>(x, xh, (int)(MK / 4));
  wprep_kernel<<<dim3(2 * DDIM / 64, DDIM / 64), 256, 0, stream>>>(W_in, winh, DDIM, 2 * DDIM);
  wprep_kernel<<<dim3(DDIM / 64, DDIM / 64), 256, 0, stream>>>(W_out, wouth, DDIM, DDIM);

  // fused GEMM1: [v | g] = x @ W_in + b_in ; v bf16, g = sigmoid -> bf16
  gemm8p<1><<<(MDIM / 256) * 8, 512, 0, stream>>>(xh, winh, b_in, nullptr, v, g, 8, DDIM);

  // chunked scan
  ssm_phase1<<<dim3(NC, BDIM), 256, 0, stream>>>(v, A, chunkh);
  ssm_phase2<<<(BDIM * DDIM) / 256, 256, 0, stream>>>(A, chunkh);
  ssm_phase3<<<dim3(NC, BDIM), 256, 0, stream>>>(v, g, A, C, chunkh, ybf);

  // GEMM2: out = y @ W_out + b_out
  gemm8p<0><<<(MDIM / 256) * 4, 512, 0, stream>>>(ybf, wouth, b_out, out, nullptr, nullptr,
                                                  4, DDIM);
}